// Round 17
// baseline (709.025 us; speedup 1.0000x reference)
//
#include <hip/hip_runtime.h>

typedef unsigned short u16;
typedef unsigned int   u32;
typedef __attribute__((ext_vector_type(8))) _Float16 f16x8;
typedef __attribute__((ext_vector_type(2))) float f32x2;
typedef __attribute__((ext_vector_type(4))) float f32x4;

constexpr int B_  = 4;
constexpr int C0  = 128;
constexpr int C1  = 32;
constexpr int H_  = 96;
constexpr int W_  = 96;
constexpr int HW  = H_ * W_;        // 9216
constexpr int PT  = 64;
constexpr int TPB = HW / PT;        // 144
constexpr int NTILE = B_ * TPB;     // 576

__device__ inline u16 f2h(float f) {
    _Float16 h = (_Float16)f;
    return __builtin_bit_cast(u16, h);
}

// ---------------------------------------------------------------------------
// Weight prep:
//  wofft[c][o*9+t]   f32 <- w_off[o][c][t]     (conv_off)
//  wdNt[k][c][o]     f32 <- w_d{N}[o][c][k]    (round-1 deform layout)
//  w0h[m][hid][ch]   f16 <- sN_{sc,sh}0_w
//  w1h[m][out][hid]  f16 <- sN_{sc,sh}1_w
__global__ __launch_bounds__(256) void k_prep(
    const float* __restrict__ w_off,
    const float* __restrict__ wd1,  const float* __restrict__ wd2,
    const float* __restrict__ s1c0, const float* __restrict__ s1h0,
    const float* __restrict__ s2c0, const float* __restrict__ s2h0,
    const float* __restrict__ s1c1, const float* __restrict__ s1h1,
    const float* __restrict__ s2c1, const float* __restrict__ s2h1,
    float* __restrict__ wofft, float* __restrict__ wd1t, float* __restrict__ wd2t,
    u16* __restrict__ w0h,     u16* __restrict__ w1h)
{
    int t = blockIdx.x * 256 + threadIdx.x;
    if (t < C0 * 18 * 9) {
        int c = t / 162, r = t % 162, o = r / 9, tap = r % 9;
        wofft[t] = w_off[(o * C0 + c) * 9 + tap];
    }
    if (t < 9 * C0 * C0) {
        int k = t / (C0 * C0), r = t % (C0 * C0), c = r / C0, o = r % C0;
        wd1t[t] = wd1[(o * C0 + c) * 9 + k];
        wd2t[t] = wd2[(o * C0 + c) * 9 + k];
    }
    if (t < 4 * C0 * C1) {
        int m = t / (C0 * C1), i = t % (C0 * C1);
        const float* s = (m == 0) ? s1c0 : (m == 1) ? s1h0 : (m == 2) ? s2c0 : s2h0;
        w0h[t] = f2h(s[i]);
    }
    if (t < 4 * C0 * C0) {
        int m = t / (C0 * C0), i = t % (C0 * C0);
        const float* s = (m == 0) ? s1c1 : (m == 1) ? s1h1 : (m == 2) ? s2c1 : s2h1;
        w1h[t] = f2h(s[i]);
    }
}

// ---------------------------------------------------------------------------
// Offset conv: 3x3, 128 -> 18 (f32, round-1 proven)
__global__ __launch_bounds__(256) void k_conv_off(
    const float* __restrict__ x0, const float* __restrict__ wofft,
    const float* __restrict__ boff, float* __restrict__ off)
{
    int bx = blockIdx.x;
    int b  = bx / TPB;
    int p0 = (bx % TPB) * PT;
    int tid = threadIdx.x;
    int p   = tid & 63;
    int cq  = __builtin_amdgcn_readfirstlane(tid >> 6);
    int pos = p0 + p;
    int h = pos / W_, w = pos % W_;

    float acc[18];
#pragma unroll
    for (int o = 0; o < 18; ++o) acc[o] = 0.f;

    for (int cc = 0; cc < 32; ++cc) {
        int c = cq * 32 + cc;
        const float* xb = x0 + ((size_t)(b * C0 + c)) * HW;
        float v[9];
#pragma unroll
        for (int t = 0; t < 9; ++t) {
            int dy = t / 3 - 1, dx = t % 3 - 1;
            int hy = h + dy, wx = w + dx;
            bool ok = (hy >= 0) & (hy < H_) & (wx >= 0) & (wx < W_);
            v[t] = ok ? xb[hy * W_ + wx] : 0.f;
        }
        const float* wr = wofft + c * 162;
#pragma unroll
        for (int o = 0; o < 18; ++o)
#pragma unroll
            for (int t = 0; t < 9; ++t)
                acc[o] = fmaf(wr[o * 9 + t], v[t], acc[o]);
    }

    __shared__ float red[4][18][PT];
#pragma unroll
    for (int o = 0; o < 18; ++o) red[cq][o][p] = acc[o];
    __syncthreads();
    for (int idx = tid; idx < 18 * PT; idx += 256) {
        int o = idx / PT, pp = idx % PT;
        float s = red[0][o][pp] + red[1][o][pp] + red[2][o][pp] + red[3][o][pp]
                + boff[o];
        off[((size_t)(b * 18 + o)) * HW + p0 + pp] = s;
    }
}

// ---------------------------------------------------------------------------
// Fused SFT via MFMA, channel-major in AND out.
// x from f32 [B,128,HW]; out f32 [B,128,HW] (LDS-transpose epilogue).
__global__ __launch_bounds__(512) void k_sft_mma(
    const float* __restrict__ xf,     // [B,128,HW]
    const float* __restrict__ x1,
    const u16* __restrict__ w0s, const u16* __restrict__ w0h,   // [128 hid][32 ch]
    const u16* __restrict__ w1s, const u16* __restrict__ w1h,   // [128 out][128 hid]
    const float* __restrict__ b0s, const float* __restrict__ b0h,
    const float* __restrict__ b1s, const float* __restrict__ b1h,
    float* __restrict__ outC)         // [B,128,HW]
{
    // 36,864 B total; otile (33,280 B) aliases the whole block after phase C
    __shared__ __align__(16) u16 smem[18432];
    u16* x1t  = smem;                  // [64][32] swz           4 KB
    u16* hid0 = smem + 2048;           // [64][128] swz         16 KB
    u16* hid1 = smem + 2048 + 8192;    // [64][128] swz         16 KB

    int bx = blockIdx.x, b = bx / TPB, p0 = (bx % TPB) * PT;
    int tid = threadIdx.x, l = tid & 63;
    int w = __builtin_amdgcn_readfirstlane(tid >> 6);
    f32x4 zz = {0.f, 0.f, 0.f, 0.f};

    for (int i = tid; i < C1 * PT; i += 512) {
        int ch = i >> 6, pos = i & 63;
        float v = x1[((size_t)(b * C1 + ch)) * HW + p0 + pos];
        x1t[pos * 32 + (ch ^ ((pos & 3) << 3))] = f2h(v);
    }
    __syncthreads();

    {   // hidden GEMM (K=32)
        int mt = w & 3, br = w >> 2;
        int pos = mt * 16 + (l & 15);
        int koff = (l >> 4) * 8;
        f16x8 a = *(const f16x8*)&x1t[pos * 32 + (koff ^ ((pos & 3) << 3))];
        const u16* w0 = br ? w0h : w0s;
        const float* bb = br ? b0h : b0s;
        u16* hrow = br ? hid1 : hid0;
#pragma unroll
        for (int nt = 0; nt < 8; ++nt) {
            int n = nt * 16 + (l & 15);
            f16x8 bfr = *(const f16x8*)&w0[n * 32 + koff];
            f32x4 h = __builtin_amdgcn_mfma_f32_16x16x32_f16(a, bfr, zz, 0, 0, 0);
            float bv = bb[n];
#pragma unroll
            for (int r = 0; r < 4; ++r) {
                float hv = h[r] + bv;
                hv = hv > 0.f ? hv : 0.1f * hv;
                int prow = mt * 16 + (l >> 4) * 4 + r;
                hrow[prow * 128 + (n ^ ((prow & 7) << 3))] = f2h(hv);
            }
        }
    }
    __syncthreads();

    f32x4 accS[4], accH[4];
#pragma unroll
    for (int nt = 0; nt < 4; ++nt) { accS[nt] = zz; accH[nt] = zz; }
    int mt = w & 3, nh = w >> 2;
    int pos = mt * 16 + (l & 15);
#pragma unroll
    for (int ks = 0; ks < 4; ++ks) {
        int kb = ks * 32 + (l >> 4) * 8;
        f16x8 aS = *(const f16x8*)&hid0[pos * 128 + (kb ^ ((pos & 7) << 3))];
        f16x8 aH = *(const f16x8*)&hid1[pos * 128 + (kb ^ ((pos & 7) << 3))];
#pragma unroll
        for (int nt = 0; nt < 4; ++nt) {
            int n = nh * 64 + nt * 16 + (l & 15);
            f16x8 bS = *(const f16x8*)&w1s[n * 128 + kb];
            f16x8 bH = *(const f16x8*)&w1h[n * 128 + kb];
            accS[nt] = __builtin_amdgcn_mfma_f32_16x16x32_f16(aS, bS, accS[nt], 0, 0, 0);
            accH[nt] = __builtin_amdgcn_mfma_f32_16x16x32_f16(aH, bH, accH[nt], 0, 0, 0);
        }
    }
    __syncthreads();                       // hidt reads done -> reuse as otile

    // Phase D: epilogue -> otile [128 o][65 pos] f32 (padded, conflict-free)
    float* otile = (float*)smem;
#pragma unroll
    for (int nt = 0; nt < 4; ++nt) {
        int n = nh * 64 + nt * 16 + (l & 15);
        float scb = b1s[n], shb = b1h[n];
        const float* xp = xf + ((size_t)(b * C0 + n)) * HW + p0 + mt * 16 + (l >> 4) * 4;
        f32x4 x4 = *(const f32x4*)xp;
#pragma unroll
        for (int r = 0; r < 4; ++r) {
            float scale = accS[nt][r] + scb + 1.f;
            float shift = accH[nt][r] + shb;
            otile[n * 65 + mt * 16 + (l >> 4) * 4 + r] = x4[r] * scale + shift;
        }
    }
    __syncthreads();

    // coalesced channel-major writeback: 128 rows x 256 B
    for (int i = tid; i < 2048; i += 512) {
        int o = i >> 4, seg = i & 15;
        *(f32x4*)&outC[((size_t)(b * C0 + o)) * HW + p0 + seg * 4]
            = *(const f32x4*)&otile[o * 65 + seg * 4];
    }
}

// ---------------------------------------------------------------------------
// Deformable conv 3x3, f32 with PACKED accumulate (v_pk_fma_f32).
// Round-1 proven structure: channel-major gather, samp LDS, s_load weights.
// MODE 0: ReLU -> f32 [B,128,HW].  MODE 1: + bias + x0 residual -> d_out.
template <int MODE>
__global__ __launch_bounds__(512) void k_deform_pk(
    const float* __restrict__ x,     // [B,128,HW] f32
    const float* __restrict__ off,   // [B,18,HW]
    const float* __restrict__ wdt,   // [9][128 c][128 o] f32
    const float* __restrict__ bias,
    const float* __restrict__ x0,    // MODE 1 residual
    float* __restrict__ out)         // [B,128,HW]
{
    __shared__ float samp[C0][PT];   // 32 KB
    __shared__ int   acy[9][PT];
    __shared__ int   acx[9][PT];
    __shared__ float awy[9][PT];
    __shared__ float awx[9][PT];

    int bx = blockIdx.x;
    bx = (bx & 7) * (NTILE / 8) + (bx >> 3);   // XCD swizzle
    int b  = bx / TPB;
    int p0 = (bx % TPB) * PT;
    int tid = threadIdx.x;
    int p   = tid & 63;
    int g   = __builtin_amdgcn_readfirstlane(tid >> 6);   // 0..7

    for (int idx = tid; idx < 9 * PT; idx += 512) {
        int k = idx >> 6, pp = idx & 63;
        int pos = p0 + pp;
        int h = pos / W_, w = pos % W_;
        float dy = off[((size_t)(b * 18 + 2 * k)) * HW + pos];
        float dx = off[((size_t)(b * 18 + 2 * k + 1)) * HW + pos];
        float py = dy + (float)(h + k / 3 - 1);
        float px = dx + (float)(w + k % 3 - 1);
        float y0f = floorf(py), x0f = floorf(px);
        acy[k][pp] = (int)y0f;
        acx[k][pp] = (int)x0f;
        awy[k][pp] = py - y0f;
        awx[k][pp] = px - x0f;
    }
    __syncthreads();

    f32x2 acc2[8];
#pragma unroll
    for (int j = 0; j < 8; ++j) acc2[j] = (f32x2){0.f, 0.f};

    for (int k = 0; k < 9; ++k) {
        // Gather phase (round-1 proven): this thread fills channels
        // g*16..g*16+15 at column p
        int   y0 = acy[k][p], xi = acx[k][p];
        float wy = awy[k][p], wx = awx[k][p];
        bool vy0 = (y0 >= 0) & (y0 < H_);
        bool vy1 = (y0 + 1 >= 0) & (y0 + 1 < H_);
        bool vx0 = (xi >= 0) & (xi < W_);
        bool vx1 = (xi + 1 >= 0) & (xi + 1 < W_);
        float w00 = (vy0 & vx0) ? (1.f - wy) * (1.f - wx) : 0.f;
        float w01 = (vy0 & vx1) ? (1.f - wy) * wx         : 0.f;
        float w10 = (vy1 & vx0) ? wy * (1.f - wx)         : 0.f;
        float w11 = (vy1 & vx1) ? wy * wx                 : 0.f;
        int iy0 = min(max(y0, 0), H_ - 1),     iy1 = min(max(y0 + 1, 0), H_ - 1);
        int ix0 = min(max(xi, 0), W_ - 1),     ix1 = min(max(xi + 1, 0), W_ - 1);
        int i00 = iy0 * W_ + ix0, i01 = iy0 * W_ + ix1;
        int i10 = iy1 * W_ + ix0, i11 = iy1 * W_ + ix1;
#pragma unroll 4
        for (int cc = 0; cc < 16; ++cc) {
            int c = g * 16 + cc;
            const float* xb = x + ((size_t)(b * C0 + c)) * HW;
            samp[c][p] = xb[i00] * w00 + xb[i01] * w01
                       + xb[i10] * w10 + xb[i11] * w11;
        }
        __syncthreads();

        // Accumulate phase: weight-stationary, 16 outputs (8 f32x2) per thread
        const float* wk = wdt + (size_t)k * C0 * C0 + g * 16;
        for (int c = 0; c < C0; ++c) {
            float s = samp[c][p];
            const f32x2* wr2 = (const f32x2*)(wk + c * C0);   // uniform -> s_load
            f32x2 sv = {s, s};
#pragma unroll
            for (int j = 0; j < 8; ++j)
                acc2[j] = sv * wr2[j] + acc2[j];              // v_pk_fma_f32
        }
        __syncthreads();
    }

#pragma unroll
    for (int j = 0; j < 8; ++j) {
#pragma unroll
        for (int e = 0; e < 2; ++e) {
            int o = g * 16 + 2 * j + e;
            float v = acc2[j][e] + bias[o];
            size_t oi = ((size_t)(b * C0 + o)) * HW + p0 + p;
            if (MODE == 0) v = v > 0.f ? v : 0.f;
            else           v += x0[oi];
            out[oi] = v;
        }
    }
}

// ---------------------------------------------------------------------------
// Workspace layout (bytes)
constexpr size_t WB_OFF   = 0;            // f32 [B,18,HW]        2,654,208
constexpr size_t WB_WOFFT = 2654208;      // f32 [128][162]          82,944
constexpr size_t WB_W0H   = 2737152;      // f16 [4][128][32]        32,768
constexpr size_t WB_W1H   = 2769920;      // f16 [4][128][128]      131,072
constexpr size_t WB_WDT1  = 2900992;      // f32 [9][128][128]      589,824
constexpr size_t WB_WDT2  = 3490816;      // f32 [9][128][128]      589,824
constexpr size_t WB_TA    = 4080640;      // f32 [B,128,HW]      18,874,368
constexpr size_t WB_TB    = 22955008;     // f32 [B,128,HW]      18,874,368
// total 41,829,376 B

extern "C" void kernel_launch(void* const* d_in, const int* in_sizes, int n_in,
                              void* d_out, int out_size, void* d_ws, size_t ws_size,
                              hipStream_t stream)
{
    const float* x0      = (const float*)d_in[0];
    const float* x1      = (const float*)d_in[1];
    const float* w_off   = (const float*)d_in[2];
    const float* b_off   = (const float*)d_in[3];
    const float* s1_sc0w = (const float*)d_in[4];
    const float* s1_sc0b = (const float*)d_in[5];
    const float* s1_sc1w = (const float*)d_in[6];
    const float* s1_sc1b = (const float*)d_in[7];
    const float* s1_sh0w = (const float*)d_in[8];
    const float* s1_sh0b = (const float*)d_in[9];
    const float* s1_sh1w = (const float*)d_in[10];
    const float* s1_sh1b = (const float*)d_in[11];
    const float* w_d1    = (const float*)d_in[12];
    const float* b_d1    = (const float*)d_in[13];
    const float* s2_sc0w = (const float*)d_in[14];
    const float* s2_sc0b = (const float*)d_in[15];
    const float* s2_sc1w = (const float*)d_in[16];
    const float* s2_sc1b = (const float*)d_in[17];
    const float* s2_sh0w = (const float*)d_in[18];
    const float* s2_sh0b = (const float*)d_in[19];
    const float* s2_sh1w = (const float*)d_in[20];
    const float* s2_sh1b = (const float*)d_in[21];
    const float* w_d2    = (const float*)d_in[22];
    const float* b_d2    = (const float*)d_in[23];

    char* wsb = (char*)d_ws;
    float* off   = (float*)(wsb + WB_OFF);
    float* wofft = (float*)(wsb + WB_WOFFT);
    u16*   w0h   = (u16*)(wsb + WB_W0H);
    u16*   w1h   = (u16*)(wsb + WB_W1H);
    float* wd1t  = (float*)(wsb + WB_WDT1);
    float* wd2t  = (float*)(wsb + WB_WDT2);
    float* TA    = (float*)(wsb + WB_TA);
    float* TB    = (float*)(wsb + WB_TB);

    k_prep<<<1152, 256, 0, stream>>>(w_off, w_d1, w_d2,
                                     s1_sc0w, s1_sh0w, s2_sc0w, s2_sh0w,
                                     s1_sc1w, s1_sh1w, s2_sc1w, s2_sh1w,
                                     wofft, wd1t, wd2t, w0h, w1h);
    k_conv_off<<<NTILE, 256, 0, stream>>>(x0, wofft, b_off, off);
    // SFT1: x0 -> TA (channel-major)
    k_sft_mma<<<NTILE, 512, 0, stream>>>(x0, x1,
                                         w0h, w0h + 4096,
                                         w1h, w1h + 16384,
                                         s1_sc0b, s1_sh0b, s1_sc1b, s1_sh1b, TA);
    // dconv1 (packed f32): gather TA -> relu -> TB (channel-major)
    k_deform_pk<0><<<NTILE, 512, 0, stream>>>(TA, off, wd1t, b_d1, nullptr, TB);
    // SFT2: TB -> TA (channel-major)
    k_sft_mma<<<NTILE, 512, 0, stream>>>(TB, x1,
                                         w0h + 8192, w0h + 12288,
                                         w1h + 32768, w1h + 49152,
                                         s2_sc0b, s2_sh0b, s2_sc1b, s2_sh1b, TA);
    // dconv2 (packed f32): gather TA -> +bias +x0 -> d_out
    k_deform_pk<1><<<NTILE, 512, 0, stream>>>(TA, off, wd2t, b_d2, x0, (float*)d_out);
}

// Round 18
// 699.894 us; speedup vs baseline: 1.0130x; 1.0130x over previous
//
#include <hip/hip_runtime.h>

typedef unsigned short u16;
typedef unsigned int   u32;
typedef __attribute__((ext_vector_type(8))) _Float16 f16x8;
typedef __attribute__((ext_vector_type(4))) float f32x4;

constexpr int B_  = 4;
constexpr int C0  = 128;
constexpr int C1  = 32;
constexpr int H_  = 96;
constexpr int W_  = 96;
constexpr int HW  = H_ * W_;        // 9216
constexpr int PT  = 64;
constexpr int TPB = HW / PT;        // 144
constexpr int NTILE = B_ * TPB;     // 576

__device__ inline u16 f2h(float f) {
    _Float16 h = (_Float16)f;
    return __builtin_bit_cast(u16, h);
}

// ---------------------------------------------------------------------------
// Weight prep:
//  wofft[c][o*9+t]   f32 <- w_off[o][c][t]     (conv_off)
//  wdNt[k][c][o]     f32 <- w_d{N}[o][c][k]    (round-1 deform layout)
//  w0h[m][hid][ch]   f16 <- sN_{sc,sh}0_w
//  w1h[m][out][hid]  f16 <- sN_{sc,sh}1_w
__global__ __launch_bounds__(256) void k_prep(
    const float* __restrict__ w_off,
    const float* __restrict__ wd1,  const float* __restrict__ wd2,
    const float* __restrict__ s1c0, const float* __restrict__ s1h0,
    const float* __restrict__ s2c0, const float* __restrict__ s2h0,
    const float* __restrict__ s1c1, const float* __restrict__ s1h1,
    const float* __restrict__ s2c1, const float* __restrict__ s2h1,
    float* __restrict__ wofft, float* __restrict__ wd1t, float* __restrict__ wd2t,
    u16* __restrict__ w0h,     u16* __restrict__ w1h)
{
    int t = blockIdx.x * 256 + threadIdx.x;
    if (t < C0 * 18 * 9) {
        int c = t / 162, r = t % 162, o = r / 9, tap = r % 9;
        wofft[t] = w_off[(o * C0 + c) * 9 + tap];
    }
    if (t < 9 * C0 * C0) {
        int k = t / (C0 * C0), r = t % (C0 * C0), c = r / C0, o = r % C0;
        wd1t[t] = wd1[(o * C0 + c) * 9 + k];
        wd2t[t] = wd2[(o * C0 + c) * 9 + k];
    }
    if (t < 4 * C0 * C1) {
        int m = t / (C0 * C1), i = t % (C0 * C1);
        const float* s = (m == 0) ? s1c0 : (m == 1) ? s1h0 : (m == 2) ? s2c0 : s2h0;
        w0h[t] = f2h(s[i]);
    }
    if (t < 4 * C0 * C0) {
        int m = t / (C0 * C0), i = t % (C0 * C0);
        const float* s = (m == 0) ? s1c1 : (m == 1) ? s1h1 : (m == 2) ? s2c1 : s2h1;
        w1h[t] = f2h(s[i]);
    }
}

// ---------------------------------------------------------------------------
// Offset conv: 3x3, 128 -> 18 (f32, round-1 proven)
__global__ __launch_bounds__(256) void k_conv_off(
    const float* __restrict__ x0, const float* __restrict__ wofft,
    const float* __restrict__ boff, float* __restrict__ off)
{
    int bx = blockIdx.x;
    int b  = bx / TPB;
    int p0 = (bx % TPB) * PT;
    int tid = threadIdx.x;
    int p   = tid & 63;
    int cq  = __builtin_amdgcn_readfirstlane(tid >> 6);
    int pos = p0 + p;
    int h = pos / W_, w = pos % W_;

    float acc[18];
#pragma unroll
    for (int o = 0; o < 18; ++o) acc[o] = 0.f;

    for (int cc = 0; cc < 32; ++cc) {
        int c = cq * 32 + cc;
        const float* xb = x0 + ((size_t)(b * C0 + c)) * HW;
        float v[9];
#pragma unroll
        for (int t = 0; t < 9; ++t) {
            int dy = t / 3 - 1, dx = t % 3 - 1;
            int hy = h + dy, wx = w + dx;
            bool ok = (hy >= 0) & (hy < H_) & (wx >= 0) & (wx < W_);
            v[t] = ok ? xb[hy * W_ + wx] : 0.f;
        }
        const float* wr = wofft + c * 162;
#pragma unroll
        for (int o = 0; o < 18; ++o)
#pragma unroll
            for (int t = 0; t < 9; ++t)
                acc[o] = fmaf(wr[o * 9 + t], v[t], acc[o]);
    }

    __shared__ float red[4][18][PT];
#pragma unroll
    for (int o = 0; o < 18; ++o) red[cq][o][p] = acc[o];
    __syncthreads();
    for (int idx = tid; idx < 18 * PT; idx += 256) {
        int o = idx / PT, pp = idx % PT;
        float s = red[0][o][pp] + red[1][o][pp] + red[2][o][pp] + red[3][o][pp]
                + boff[o];
        off[((size_t)(b * 18 + o)) * HW + p0 + pp] = s;
    }
}

// ---------------------------------------------------------------------------
// Fused SFT via MFMA, channel-major in AND out (round-17 validated).
__global__ __launch_bounds__(512) void k_sft_mma(
    const float* __restrict__ xf,     // [B,128,HW]
    const float* __restrict__ x1,
    const u16* __restrict__ w0s, const u16* __restrict__ w0h,   // [128 hid][32 ch]
    const u16* __restrict__ w1s, const u16* __restrict__ w1h,   // [128 out][128 hid]
    const float* __restrict__ b0s, const float* __restrict__ b0h,
    const float* __restrict__ b1s, const float* __restrict__ b1h,
    float* __restrict__ outC)         // [B,128,HW]
{
    __shared__ __align__(16) u16 smem[18432];   // 36,864 B; otile aliases after C
    u16* x1t  = smem;                  // [64][32] swz           4 KB
    u16* hid0 = smem + 2048;           // [64][128] swz         16 KB
    u16* hid1 = smem + 2048 + 8192;    // [64][128] swz         16 KB

    int bx = blockIdx.x, b = bx / TPB, p0 = (bx % TPB) * PT;
    int tid = threadIdx.x, l = tid & 63;
    int w = __builtin_amdgcn_readfirstlane(tid >> 6);
    f32x4 zz = {0.f, 0.f, 0.f, 0.f};

    for (int i = tid; i < C1 * PT; i += 512) {
        int ch = i >> 6, pos = i & 63;
        float v = x1[((size_t)(b * C1 + ch)) * HW + p0 + pos];
        x1t[pos * 32 + (ch ^ ((pos & 3) << 3))] = f2h(v);
    }
    __syncthreads();

    {   // hidden GEMM (K=32)
        int mt = w & 3, br = w >> 2;
        int pos = mt * 16 + (l & 15);
        int koff = (l >> 4) * 8;
        f16x8 a = *(const f16x8*)&x1t[pos * 32 + (koff ^ ((pos & 3) << 3))];
        const u16* w0 = br ? w0h : w0s;
        const float* bb = br ? b0h : b0s;
        u16* hrow = br ? hid1 : hid0;
#pragma unroll
        for (int nt = 0; nt < 8; ++nt) {
            int n = nt * 16 + (l & 15);
            f16x8 bfr = *(const f16x8*)&w0[n * 32 + koff];
            f32x4 h = __builtin_amdgcn_mfma_f32_16x16x32_f16(a, bfr, zz, 0, 0, 0);
            float bv = bb[n];
#pragma unroll
            for (int r = 0; r < 4; ++r) {
                float hv = h[r] + bv;
                hv = hv > 0.f ? hv : 0.1f * hv;
                int prow = mt * 16 + (l >> 4) * 4 + r;
                hrow[prow * 128 + (n ^ ((prow & 7) << 3))] = f2h(hv);
            }
        }
    }
    __syncthreads();

    f32x4 accS[4], accH[4];
#pragma unroll
    for (int nt = 0; nt < 4; ++nt) { accS[nt] = zz; accH[nt] = zz; }
    int mt = w & 3, nh = w >> 2;
    int pos = mt * 16 + (l & 15);
#pragma unroll
    for (int ks = 0; ks < 4; ++ks) {
        int kb = ks * 32 + (l >> 4) * 8;
        f16x8 aS = *(const f16x8*)&hid0[pos * 128 + (kb ^ ((pos & 7) << 3))];
        f16x8 aH = *(const f16x8*)&hid1[pos * 128 + (kb ^ ((pos & 7) << 3))];
#pragma unroll
        for (int nt = 0; nt < 4; ++nt) {
            int n = nh * 64 + nt * 16 + (l & 15);
            f16x8 bS = *(const f16x8*)&w1s[n * 128 + kb];
            f16x8 bH = *(const f16x8*)&w1h[n * 128 + kb];
            accS[nt] = __builtin_amdgcn_mfma_f32_16x16x32_f16(aS, bS, accS[nt], 0, 0, 0);
            accH[nt] = __builtin_amdgcn_mfma_f32_16x16x32_f16(aH, bH, accH[nt], 0, 0, 0);
        }
    }
    __syncthreads();                       // hid reads done -> reuse as otile

    // Phase D: epilogue -> otile [128 o][65 pos] f32 (padded)
    float* otile = (float*)smem;
#pragma unroll
    for (int nt = 0; nt < 4; ++nt) {
        int n = nh * 64 + nt * 16 + (l & 15);
        float scb = b1s[n], shb = b1h[n];
        const float* xp = xf + ((size_t)(b * C0 + n)) * HW + p0 + mt * 16 + (l >> 4) * 4;
        f32x4 x4 = *(const f32x4*)xp;
#pragma unroll
        for (int r = 0; r < 4; ++r) {
            float scale = accS[nt][r] + scb + 1.f;
            float shift = accH[nt][r] + shb;
            otile[n * 65 + mt * 16 + (l >> 4) * 4 + r] = x4[r] * scale + shift;
        }
    }
    __syncthreads();

    for (int i = tid; i < 2048; i += 512) {
        int o = i >> 4, seg = i & 15;
        *(f32x4*)&outC[((size_t)(b * C0 + o)) * HW + p0 + seg * 4]
            = *(const f32x4*)&otile[o * 65 + seg * 4];
    }
}

// ---------------------------------------------------------------------------
// Deformable conv 3x3 — EXACT round-1 structure (102 µs, VALUBusy 92%,
// scalar-FMA roofline).  Only additions: XCD swizzle, MODE epilogue.
// MODE 0: ReLU -> f32 [B,128,HW].  MODE 1: + bias + x0 residual -> d_out.
template <int MODE>
__global__ __launch_bounds__(512) void k_deform(
    const float* __restrict__ x,     // [B,128,HW] f32
    const float* __restrict__ off,   // [B,18,HW]
    const float* __restrict__ wdt,   // [9][128 c][128 o] f32
    const float* __restrict__ bias,
    const float* __restrict__ x0,    // MODE 1 residual
    float* __restrict__ out)         // [B,128,HW]
{
    __shared__ float samp[C0][PT];   // 32 KB
    __shared__ int   acy[9][PT];
    __shared__ int   acx[9][PT];
    __shared__ float awy[9][PT];
    __shared__ float awx[9][PT];

    int bx = blockIdx.x;
    bx = (bx & 7) * (NTILE / 8) + (bx >> 3);   // XCD swizzle
    int b  = bx / TPB;
    int p0 = (bx % TPB) * PT;
    int tid = threadIdx.x;
    int p   = tid & 63;
    int g   = __builtin_amdgcn_readfirstlane(tid >> 6);   // 0..7

    for (int idx = tid; idx < 9 * PT; idx += 512) {
        int k = idx >> 6, pp = idx & 63;
        int pos = p0 + pp;
        int h = pos / W_, w = pos % W_;
        float dy = off[((size_t)(b * 18 + 2 * k)) * HW + pos];
        float dx = off[((size_t)(b * 18 + 2 * k + 1)) * HW + pos];
        float py = dy + (float)(h + k / 3 - 1);
        float px = dx + (float)(w + k % 3 - 1);
        float y0f = floorf(py), x0f = floorf(px);
        acy[k][pp] = (int)y0f;
        acx[k][pp] = (int)x0f;
        awy[k][pp] = py - y0f;
        awx[k][pp] = px - x0f;
    }
    __syncthreads();

    float acc[16];
#pragma unroll
    for (int i = 0; i < 16; ++i) acc[i] = 0.f;

    for (int k = 0; k < 9; ++k) {
        int   y0 = acy[k][p], xi = acx[k][p];
        float wy = awy[k][p], wx = awx[k][p];
        bool vy0 = (y0 >= 0) & (y0 < H_);
        bool vy1 = (y0 + 1 >= 0) & (y0 + 1 < H_);
        bool vx0 = (xi >= 0) & (xi < W_);
        bool vx1 = (xi + 1 >= 0) & (xi + 1 < W_);
        float w00 = (vy0 & vx0) ? (1.f - wy) * (1.f - wx) : 0.f;
        float w01 = (vy0 & vx1) ? (1.f - wy) * wx         : 0.f;
        float w10 = (vy1 & vx0) ? wy * (1.f - wx)         : 0.f;
        float w11 = (vy1 & vx1) ? wy * wx                 : 0.f;
        int iy0 = min(max(y0, 0), H_ - 1),     iy1 = min(max(y0 + 1, 0), H_ - 1);
        int ix0 = min(max(xi, 0), W_ - 1),     ix1 = min(max(xi + 1, 0), W_ - 1);
        int i00 = iy0 * W_ + ix0, i01 = iy0 * W_ + ix1;
        int i10 = iy1 * W_ + ix0, i11 = iy1 * W_ + ix1;
#pragma unroll 4
        for (int cc = 0; cc < 16; ++cc) {
            int c = g * 16 + cc;
            const float* xb = x + ((size_t)(b * C0 + c)) * HW;
            samp[c][p] = xb[i00] * w00 + xb[i01] * w01
                       + xb[i10] * w10 + xb[i11] * w11;
        }
        __syncthreads();

        // Accumulate: weight-stationary, 16 outputs/thread, s_load weights
        const float* wk = wdt + (size_t)k * C0 * C0 + g * 16;
        for (int c = 0; c < C0; ++c) {
            float s = samp[c][p];
            const float* wr = wk + c * C0;   // uniform -> s_load_dwordx16
#pragma unroll
            for (int i = 0; i < 16; ++i) acc[i] = fmaf(wr[i], s, acc[i]);
        }
        __syncthreads();
    }

#pragma unroll
    for (int i = 0; i < 16; ++i) {
        int o = g * 16 + i;
        float v = acc[i] + bias[o];
        size_t oi = ((size_t)(b * C0 + o)) * HW + p0 + p;
        if (MODE == 0) v = v > 0.f ? v : 0.f;
        else           v += x0[oi];
        out[oi] = v;
    }
}

// ---------------------------------------------------------------------------
// Workspace layout (bytes)
constexpr size_t WB_OFF   = 0;            // f32 [B,18,HW]        2,654,208
constexpr size_t WB_WOFFT = 2654208;      // f32 [128][162]          82,944
constexpr size_t WB_W0H   = 2737152;      // f16 [4][128][32]        32,768
constexpr size_t WB_W1H   = 2769920;      // f16 [4][128][128]      131,072
constexpr size_t WB_WDT1  = 2900992;      // f32 [9][128][128]      589,824
constexpr size_t WB_WDT2  = 3490816;      // f32 [9][128][128]      589,824
constexpr size_t WB_TA    = 4080640;      // f32 [B,128,HW]      18,874,368
constexpr size_t WB_TB    = 22955008;     // f32 [B,128,HW]      18,874,368
// total 41,829,376 B

extern "C" void kernel_launch(void* const* d_in, const int* in_sizes, int n_in,
                              void* d_out, int out_size, void* d_ws, size_t ws_size,
                              hipStream_t stream)
{
    const float* x0      = (const float*)d_in[0];
    const float* x1      = (const float*)d_in[1];
    const float* w_off   = (const float*)d_in[2];
    const float* b_off   = (const float*)d_in[3];
    const float* s1_sc0w = (const float*)d_in[4];
    const float* s1_sc0b = (const float*)d_in[5];
    const float* s1_sc1w = (const float*)d_in[6];
    const float* s1_sc1b = (const float*)d_in[7];
    const float* s1_sh0w = (const float*)d_in[8];
    const float* s1_sh0b = (const float*)d_in[9];
    const float* s1_sh1w = (const float*)d_in[10];
    const float* s1_sh1b = (const float*)d_in[11];
    const float* w_d1    = (const float*)d_in[12];
    const float* b_d1    = (const float*)d_in[13];
    const float* s2_sc0w = (const float*)d_in[14];
    const float* s2_sc0b = (const float*)d_in[15];
    const float* s2_sc1w = (const float*)d_in[16];
    const float* s2_sc1b = (const float*)d_in[17];
    const float* s2_sh0w = (const float*)d_in[18];
    const float* s2_sh0b = (const float*)d_in[19];
    const float* s2_sh1w = (const float*)d_in[20];
    const float* s2_sh1b = (const float*)d_in[21];
    const float* w_d2    = (const float*)d_in[22];
    const float* b_d2    = (const float*)d_in[23];

    char* wsb = (char*)d_ws;
    float* off   = (float*)(wsb + WB_OFF);
    float* wofft = (float*)(wsb + WB_WOFFT);
    u16*   w0h   = (u16*)(wsb + WB_W0H);
    u16*   w1h   = (u16*)(wsb + WB_W1H);
    float* wd1t  = (float*)(wsb + WB_WDT1);
    float* wd2t  = (float*)(wsb + WB_WDT2);
    float* TA    = (float*)(wsb + WB_TA);
    float* TB    = (float*)(wsb + WB_TB);

    k_prep<<<1152, 256, 0, stream>>>(w_off, w_d1, w_d2,
                                     s1_sc0w, s1_sh0w, s2_sc0w, s2_sh0w,
                                     s1_sc1w, s1_sh1w, s2_sc1w, s2_sh1w,
                                     wofft, wd1t, wd2t, w0h, w1h);
    k_conv_off<<<NTILE, 256, 0, stream>>>(x0, wofft, b_off, off);
    // SFT1: x0 -> TA (channel-major)
    k_sft_mma<<<NTILE, 512, 0, stream>>>(x0, x1,
                                         w0h, w0h + 4096,
                                         w1h, w1h + 16384,
                                         s1_sc0b, s1_sh0b, s1_sc1b, s1_sh1b, TA);
    // dconv1 (f32 scalar, round-1): gather TA -> relu -> TB (channel-major)
    k_deform<0><<<NTILE, 512, 0, stream>>>(TA, off, wd1t, b_d1, nullptr, TB);
    // SFT2: TB -> TA (channel-major)
    k_sft_mma<<<NTILE, 512, 0, stream>>>(TB, x1,
                                         w0h + 8192, w0h + 12288,
                                         w1h + 32768, w1h + 49152,
                                         s2_sc0b, s2_sh0b, s2_sc1b, s2_sh1b, TA);
    // dconv2 (f32 scalar, round-1): gather TA -> +bias +x0 -> d_out
    k_deform<1><<<NTILE, 512, 0, stream>>>(TA, off, wd2t, b_d2, x0, (float*)d_out);
}